// Round 9
// baseline (794.198 us; speedup 1.0000x reference)
//
#include <hip/hip_runtime.h>
#include <hip/hip_bf16.h>

#define B_     4
#define L_     2048
#define D_     1024
#define MAXLEN 2048
#define N_     3072   // D*(ORDER+1)
#define K_     1024
#define KP     40     // padded LDS row (bf16 elems): 80 B rows, 16B-aligned

typedef __attribute__((ext_vector_type(8))) short short8;
typedef __attribute__((ext_vector_type(4))) short short4v;
typedef __attribute__((ext_vector_type(4))) float f32x4;

__device__ __forceinline__ short f2bf(float x) {
    return __builtin_bit_cast(short, (__bf16)x);
}
__device__ __forceinline__ float bf2f(short h) {
    return (float)__builtin_bit_cast(__bf16, h);
}

// ---------------------------------------------------------------------------
// Prepass: W [K][N] fp32  ->  WtH/WtL [N][K] bf16 (hi/lo split), transposed.
// ---------------------------------------------------------------------------
__global__ __launch_bounds__(256) void wsplit_kernel(
    const float* __restrict__ W, short* __restrict__ WtH, short* __restrict__ WtL)
{
    __shared__ float lds[64][65];
    const int n0 = blockIdx.x * 64;
    const int k0 = blockIdx.y * 64;
    const int t  = threadIdx.x;
    const int nc = t & 63;
#pragma unroll
    for (int i = 0; i < 16; ++i) {
        const int kr = i * 4 + (t >> 6);
        lds[kr][nc] = W[(size_t)(k0 + kr) * N_ + n0 + nc];
    }
    __syncthreads();
    const int kg = (t & 15) * 4;
#pragma unroll
    for (int r = 0; r < 4; ++r) {
        const int nr = (t >> 4) + r * 16;
        short4v hv, lv;
#pragma unroll
        for (int j = 0; j < 4; ++j) {
            const float x = lds[kg + j][nr];
            const short h = f2bf(x);
            hv[j] = h;
            lv[j] = f2bf(x - bf2f(h));
        }
        const size_t o = (size_t)(n0 + nr) * K_ + k0 + kg;
        *(short4v*)&WtH[o] = hv;
        *(short4v*)&WtL[o] = lv;
    }
}

// ---------------------------------------------------------------------------
// GEMM via bf16x3 split MFMA (unchanged from R2).
// ---------------------------------------------------------------------------
__global__ __launch_bounds__(256) void gemm_mfma_kernel(
    const float* __restrict__ X, const short* __restrict__ WtH,
    const short* __restrict__ WtL, const float* __restrict__ bias,
    float* __restrict__ p0, float* __restrict__ p1, float* __restrict__ p2)
{
    __shared__ __align__(16) short Ah[128][KP];
    __shared__ __align__(16) short Al[128][KP];
    __shared__ __align__(16) short Bh[128][KP];
    __shared__ __align__(16) short Bl[128][KP];

    const int tid = threadIdx.x;
    const int m0 = blockIdx.y * 128;
    const int n0 = blockIdx.x * 128;

    const int lane = tid & 63;
    const int wave = tid >> 6;
    const int wr = wave >> 1;
    const int wc = wave & 1;
    const int fr = lane & 15;
    const int fq = lane >> 4;

    const int srow  = tid >> 1;
    const int shalf = (tid & 1) * 16;

    f32x4 acc[4][4];
#pragma unroll
    for (int m = 0; m < 4; ++m)
#pragma unroll
        for (int n = 0; n < 4; ++n) acc[m][n] = (f32x4){0.f, 0.f, 0.f, 0.f};

    const float* xp  = &X[(size_t)(m0 + srow) * K_ + shalf];
    const short* bhp = &WtH[(size_t)(n0 + srow) * K_ + shalf];
    const short* blp = &WtL[(size_t)(n0 + srow) * K_ + shalf];

    for (int k0 = 0; k0 < K_; k0 += 32) {
        float xv[16];
        *(float4*)&xv[0]  = *(const float4*)&xp[k0];
        *(float4*)&xv[4]  = *(const float4*)&xp[k0 + 4];
        *(float4*)&xv[8]  = *(const float4*)&xp[k0 + 8];
        *(float4*)&xv[12] = *(const float4*)&xp[k0 + 12];
        short8 ah[2], al[2];
#pragma unroll
        for (int g = 0; g < 2; ++g)
#pragma unroll
            for (int j = 0; j < 8; ++j) {
                const float x = xv[g * 8 + j];
                const short h = f2bf(x);
                ah[g][j] = h;
                al[g][j] = f2bf(x - bf2f(h));
            }
        *(short8*)&Ah[srow][shalf]     = ah[0];
        *(short8*)&Ah[srow][shalf + 8] = ah[1];
        *(short8*)&Al[srow][shalf]     = al[0];
        *(short8*)&Al[srow][shalf + 8] = al[1];
        *(short8*)&Bh[srow][shalf]     = *(const short8*)&bhp[k0];
        *(short8*)&Bh[srow][shalf + 8] = *(const short8*)&bhp[k0 + 8];
        *(short8*)&Bl[srow][shalf]     = *(const short8*)&blp[k0];
        *(short8*)&Bl[srow][shalf + 8] = *(const short8*)&blp[k0 + 8];
        __syncthreads();

        short8 aH[4], aL[4], bH[4], bL[4];
#pragma unroll
        for (int m = 0; m < 4; ++m) {
            aH[m] = *(const short8*)&Ah[wr * 64 + m * 16 + fr][fq * 8];
            aL[m] = *(const short8*)&Al[wr * 64 + m * 16 + fr][fq * 8];
        }
#pragma unroll
        for (int n = 0; n < 4; ++n) {
            bH[n] = *(const short8*)&Bh[wc * 64 + n * 16 + fr][fq * 8];
            bL[n] = *(const short8*)&Bl[wc * 64 + n * 16 + fr][fq * 8];
        }
#pragma unroll
        for (int m = 0; m < 4; ++m)
#pragma unroll
            for (int n = 0; n < 4; ++n) {
                acc[m][n] = __builtin_amdgcn_mfma_f32_16x16x32_bf16(aH[m], bH[n], acc[m][n], 0, 0, 0);
                acc[m][n] = __builtin_amdgcn_mfma_f32_16x16x32_bf16(aH[m], bL[n], acc[m][n], 0, 0, 0);
                acc[m][n] = __builtin_amdgcn_mfma_f32_16x16x32_bf16(aL[m], bH[n], acc[m][n], 0, 0, 0);
            }
        __syncthreads();
    }

    const int s = n0 >> 10;
    float* outp = (s == 0) ? p0 : ((s == 1) ? p1 : p2);
    const int csub = n0 & 1023;
#pragma unroll
    for (int n = 0; n < 4; ++n) {
        const int gcol = wc * 64 + n * 16 + fr;
        const float bv = bias[n0 + gcol];
        const int col = csub + gcol;
#pragma unroll
        for (int m = 0; m < 4; ++m) {
            const int rowb = m0 + wr * 64 + m * 16 + fq * 4;
#pragma unroll
            for (int j = 0; j < 4; ++j)
                outp[(size_t)(rowb + j) * D_ + col] = acc[m][n][j] + bv;
        }
    }
}

// ---------------------------------------------------------------------------
// Causal depthwise conv stage:
//   vout[b,l,d] = ( sum_{t<=l} vin[b,t,d] * filt[l-t,d] ) * gate[b,l,d]
// R8 = R7 with the window-load axis bug fixed:
//  - filter circular buffer stored as f4[48][128][4] = [quad-row][chan][tap]
//    so a 4-TAP window quad for channel dl is ONE aligned ds_read_b128 at
//    &f4[x>>2][dl][0] (x = c_cur+r0+K is always a multiple of 4).
//    (R7 read 4 consecutive CHANNELS of one row — wrong axis.)
//  - staging remapped to match: each thread loads 4 taps x 1 channel from
//    global (4 coalesced dword loads) and writes one b128 quad.
//  - 512-thread blocks, 128 KB LDS -> exactly 1 block/CU, 256 blocks.
//  - static 64-reg circular filter window fwq[16] (f32x4), register index
//    compile-time after unroll -> zero shift movs; refresh 4 quads per
//    4-step group into provably-dead regs.
//  - vv ping-pong: next step's v reads issued during current step.
// ---------------------------------------------------------------------------
__global__ __launch_bounds__(512, 1) void conv_stage_kernel(
    const float* __restrict__ vin, const float* __restrict__ filt,
    const float* __restrict__ gate, float* __restrict__ vout)
{
    __shared__ float v_lds[64][128];        // [t][d]            32 KB
    __shared__ float f4[48][128][4];        // [qrow][chan][tap] 96 KB circular

    const int d0 = blockIdx.x * 128;
    const int yp = blockIdx.y;         // 0..7
    const int b  = blockIdx.z;
    const int tid = threadIdx.x;
    const int dl = tid & 127;          // channel within tile
    const int rg = tid >> 7;           // 0..3
    const int r0 = rg * 32;            // first of this thread's 32 rows

    const int sr = tid >> 5;           // v staging row 0..15
    const int sc = (tid & 31) * 4;     // v staging col group
    const int fch = tid & 127;         // f staging channel
    const int fq0 = tid >> 7;          // f staging quad-row base 0..3

    const float* vin_b = vin + (size_t)b * L_ * D_;

#define FWQ(i) fwq[((i) & 63) >> 2][(i) & 3]

    for (int half = 0; half < 2; ++half) {
        const int yt = (half == 0) ? yp : (15 - yp);
        const int l0 = yt * 128;
        const int ntiles = 2 * yt + 2;     // t0 = 0 .. l0+64
        int c_cur = l0 % 192;              // sigma base (multiple of 64)

        __syncthreads();   // protect LDS from previous half's compute
        // ---- prologue: stage v tile 0 + full 192-row (48 quad-row) filter ----
        {
#pragma unroll
            for (int s = 0; s < 4; ++s) {
                const float4 q = *(const float4*)&vin_b[(size_t)(sr + 16*s) * D_ + d0 + sc];
                *(float4*)&v_lds[sr + 16*s][sc] = q;
            }
            const int base0 = l0 - 63;
#pragma unroll
            for (int s = 0; s < 12; ++s) {
                const int qr = fq0 + 4*s;            // 0..47
                int qsg = (c_cur >> 2) + qr; if (qsg >= 48) qsg -= 48;
                f32x4 q;
#pragma unroll
                for (int e = 0; e < 4; ++e) {
                    const int a = base0 + 4*qr + e;
                    float fv = 0.f;
                    if (a >= 0 && a < MAXLEN) fv = filt[(size_t)a * D_ + d0 + fch];
                    q[e] = fv;
                }
                *(f32x4*)&f4[qsg][fch][0] = q;
            }
        }
        __syncthreads();

        // ---- prefetch tile 1 (ntiles >= 2 always) ----
        float4 pv[4];
        f32x4 pf4[4];
#pragma unroll
        for (int s = 0; s < 4; ++s)
            pv[s] = *(const float4*)&vin_b[(size_t)(64 + sr + 16*s) * D_ + d0 + sc];
        {
            const int base1 = l0 - 127;   // l0 - 64 - 63
#pragma unroll
            for (int s = 0; s < 4; ++s) {
                const int qr = fq0 + 4*s;            // 0..15
#pragma unroll
                for (int e = 0; e < 4; ++e) {
                    const int a = base1 + 4*qr + e;
                    float fv = 0.f;
                    if (a >= 0 && a < MAXLEN) fv = filt[(size_t)a * D_ + d0 + fch];
                    pf4[s][e] = fv;
                }
            }
        }

        float acc[32];
#pragma unroll
        for (int j = 0; j < 32; ++j) acc[j] = 0.f;

        for (int ti = 0; ti < ntiles; ++ti) {
            // ---- compute tile ti ----
            // init static circular window: i-values K=48..95 -> regs
            // {12..15, 0..7}; regs 8..11 land via the si=0 refresh.
            f32x4 fwq[16];
#pragma unroll
            for (int s2 = 0; s2 < 12; ++s2) {
                const int K = 48 + 4*s2;
                int x = c_cur + r0 + K; if (x >= 192) x -= 192;
                fwq[(K & 63) >> 2] = *(const f32x4*)&f4[x >> 2][dl][0];
            }
            float vv[2][4];
#pragma unroll
            for (int u = 0; u < 4; ++u) vv[0][u] = v_lds[u][dl];

#pragma unroll
            for (int si = 0; si < 16; ++si) {
                const int tb = 4 * si;
                // refresh window for a FUTURE group (target regs dead now)
                if ((si & 3) == 0 && si < 12) {
                    const int g = si >> 2;
#pragma unroll
                    for (int s2 = 0; s2 < 4; ++s2) {
                        const int K = 32 - 16*g + 4*s2;
                        int x = c_cur + r0 + K; if (x >= 192) x -= 192;
                        fwq[(K & 63) >> 2] = *(const f32x4*)&f4[x >> 2][dl][0];
                    }
                }
                // ping-pong: issue next step's v reads
                if (si < 15) {
#pragma unroll
                    for (int u = 0; u < 4; ++u)
                        vv[(si + 1) & 1][u] = v_lds[tb + 4 + u][dl];
                }
                // 128 FMAs; filter tap f[l-t] via static circular reg index
#pragma unroll
                for (int u = 0; u < 4; ++u)
#pragma unroll
                    for (int j = 0; j < 32; ++j)
                        acc[j] += vv[si & 1][u] * FWQ(63 - tb + j - u);
            }

            // ---- stage tile ti+1 from prefetch regs, prefetch ti+2 ----
            if (ti + 1 < ntiles) {
                int c_next = c_cur - 64; if (c_next < 0) c_next += 192;
                __syncthreads();
#pragma unroll
                for (int s = 0; s < 4; ++s)
                    *(float4*)&v_lds[sr + 16*s][sc] = pv[s];
#pragma unroll
                for (int s = 0; s < 4; ++s) {
                    const int qsg = (c_next >> 2) + fq0 + 4*s;   // < 48
                    *(f32x4*)&f4[qsg][fch][0] = pf4[s];
                }
                __syncthreads();
                if (ti + 2 < ntiles) {
                    const int t0n = 64 * (ti + 2);
#pragma unroll
                    for (int s = 0; s < 4; ++s)
                        pv[s] = *(const float4*)&vin_b[(size_t)(t0n + sr + 16*s) * D_ + d0 + sc];
                    const int basen = l0 - t0n - 63;
#pragma unroll
                    for (int s = 0; s < 4; ++s) {
                        const int qr = fq0 + 4*s;
#pragma unroll
                        for (int e = 0; e < 4; ++e) {
                            const int a = basen + 4*qr + e;
                            float fv = 0.f;
                            if (a >= 0 && a < MAXLEN) fv = filt[(size_t)a * D_ + d0 + fch];
                            pf4[s][e] = fv;
                        }
                    }
                }
                c_cur = c_next;
            }
        }

        // ---- gated epilogue ----
        const size_t off = (size_t)b * L_ * D_ + (size_t)l0 * D_ + d0 + dl;
#pragma unroll
        for (int j = 0; j < 32; ++j) {
            const size_t idx = off + (size_t)(r0 + j) * D_;
            vout[idx] = acc[j] * gate[idx];
        }
    }
#undef FWQ
}

extern "C" void kernel_launch(void* const* d_in, const int* in_sizes, int n_in,
                              void* d_out, int out_size, void* d_ws, size_t ws_size,
                              hipStream_t stream) {
    const float* x  = (const float*)d_in[0];   // (B, L, D)
    const float* w  = (const float*)d_in[1];   // (D, 3D)
    const float* bb = (const float*)d_in[2];   // (3D,)
    const float* ft = (const float*)d_in[3];   // (2, 1, MAXLEN, D)
    float* out = (float*)d_out;                // (B, L, D)

    float* p0 = (float*)d_ws;                  // (B*L, D) planar slices
    float* p1 = p0 + (size_t)B_ * L_ * D_;
    float* p2 = p1 + (size_t)B_ * L_ * D_;

    // W split scratch lives in d_out; final conv overwrites all of d_out.
    short* WtH = (short*)d_out;
    short* WtL = WtH + (size_t)N_ * K_;

    // 0) transpose + bf16-split W
    wsplit_kernel<<<dim3(N_ / 64, K_ / 64), 256, 0, stream>>>(w, WtH, WtL);

    // 1) projection GEMM (MFMA bf16x3) -> p0, p1, p2
    gemm_mfma_kernel<<<dim3(N_ / 128, (B_ * L_) / 128), 256, 0, stream>>>(
        x, WtH, WtL, bb, p0, p1, p2);

    // 2) stage 0: v1 = conv(p0, f0) * p1   (in place over p1 — pointwise self-index)
    conv_stage_kernel<<<dim3(D_ / 128, 8, B_), 512, 0, stream>>>(
        p0, ft, p1, p1);

    // 3) stage 1: out = conv(v1, f1) * p2
    conv_stage_kernel<<<dim3(D_ / 128, 8, B_), 512, 0, stream>>>(
        p1, ft + (size_t)MAXLEN * D_, p2, out);
}

// Round 10
// 793.761 us; speedup vs baseline: 1.0006x; 1.0006x over previous
//
#include <hip/hip_runtime.h>
#include <hip/hip_bf16.h>

#define B_     4
#define L_     2048
#define D_     1024
#define MAXLEN 2048
#define N_     3072   // D*(ORDER+1)
#define K_     1024
#define KP     40     // padded LDS row (bf16 elems): 80 B rows, 16B-aligned

typedef __attribute__((ext_vector_type(8))) short short8;
typedef __attribute__((ext_vector_type(4))) short short4v;
typedef __attribute__((ext_vector_type(4))) float f32x4;

__device__ __forceinline__ short f2bf(float x) {
    return __builtin_bit_cast(short, (__bf16)x);
}
__device__ __forceinline__ float bf2f(short h) {
    return (float)__builtin_bit_cast(__bf16, h);
}

// ---------------------------------------------------------------------------
// Prepass: W [K][N] fp32  ->  WtH/WtL [N][K] bf16 (hi/lo split), transposed.
// ---------------------------------------------------------------------------
__global__ __launch_bounds__(256) void wsplit_kernel(
    const float* __restrict__ W, short* __restrict__ WtH, short* __restrict__ WtL)
{
    __shared__ float lds[64][65];
    const int n0 = blockIdx.x * 64;
    const int k0 = blockIdx.y * 64;
    const int t  = threadIdx.x;
    const int nc = t & 63;
#pragma unroll
    for (int i = 0; i < 16; ++i) {
        const int kr = i * 4 + (t >> 6);
        lds[kr][nc] = W[(size_t)(k0 + kr) * N_ + n0 + nc];
    }
    __syncthreads();
    const int kg = (t & 15) * 4;
#pragma unroll
    for (int r = 0; r < 4; ++r) {
        const int nr = (t >> 4) + r * 16;
        short4v hv, lv;
#pragma unroll
        for (int j = 0; j < 4; ++j) {
            const float x = lds[kg + j][nr];
            const short h = f2bf(x);
            hv[j] = h;
            lv[j] = f2bf(x - bf2f(h));
        }
        const size_t o = (size_t)(n0 + nr) * K_ + k0 + kg;
        *(short4v*)&WtH[o] = hv;
        *(short4v*)&WtL[o] = lv;
    }
}

// ---------------------------------------------------------------------------
// GEMM via bf16x3 split MFMA (unchanged from R2).
// ---------------------------------------------------------------------------
__global__ __launch_bounds__(256) void gemm_mfma_kernel(
    const float* __restrict__ X, const short* __restrict__ WtH,
    const short* __restrict__ WtL, const float* __restrict__ bias,
    float* __restrict__ p0, float* __restrict__ p1, float* __restrict__ p2)
{
    __shared__ __align__(16) short Ah[128][KP];
    __shared__ __align__(16) short Al[128][KP];
    __shared__ __align__(16) short Bh[128][KP];
    __shared__ __align__(16) short Bl[128][KP];

    const int tid = threadIdx.x;
    const int m0 = blockIdx.y * 128;
    const int n0 = blockIdx.x * 128;

    const int lane = tid & 63;
    const int wave = tid >> 6;
    const int wr = wave >> 1;
    const int wc = wave & 1;
    const int fr = lane & 15;
    const int fq = lane >> 4;

    const int srow  = tid >> 1;
    const int shalf = (tid & 1) * 16;

    f32x4 acc[4][4];
#pragma unroll
    for (int m = 0; m < 4; ++m)
#pragma unroll
        for (int n = 0; n < 4; ++n) acc[m][n] = (f32x4){0.f, 0.f, 0.f, 0.f};

    const float* xp  = &X[(size_t)(m0 + srow) * K_ + shalf];
    const short* bhp = &WtH[(size_t)(n0 + srow) * K_ + shalf];
    const short* blp = &WtL[(size_t)(n0 + srow) * K_ + shalf];

    for (int k0 = 0; k0 < K_; k0 += 32) {
        float xv[16];
        *(float4*)&xv[0]  = *(const float4*)&xp[k0];
        *(float4*)&xv[4]  = *(const float4*)&xp[k0 + 4];
        *(float4*)&xv[8]  = *(const float4*)&xp[k0 + 8];
        *(float4*)&xv[12] = *(const float4*)&xp[k0 + 12];
        short8 ah[2], al[2];
#pragma unroll
        for (int g = 0; g < 2; ++g)
#pragma unroll
            for (int j = 0; j < 8; ++j) {
                const float x = xv[g * 8 + j];
                const short h = f2bf(x);
                ah[g][j] = h;
                al[g][j] = f2bf(x - bf2f(h));
            }
        *(short8*)&Ah[srow][shalf]     = ah[0];
        *(short8*)&Ah[srow][shalf + 8] = ah[1];
        *(short8*)&Al[srow][shalf]     = al[0];
        *(short8*)&Al[srow][shalf + 8] = al[1];
        *(short8*)&Bh[srow][shalf]     = *(const short8*)&bhp[k0];
        *(short8*)&Bh[srow][shalf + 8] = *(const short8*)&bhp[k0 + 8];
        *(short8*)&Bl[srow][shalf]     = *(const short8*)&blp[k0];
        *(short8*)&Bl[srow][shalf + 8] = *(const short8*)&blp[k0 + 8];
        __syncthreads();

        short8 aH[4], aL[4], bH[4], bL[4];
#pragma unroll
        for (int m = 0; m < 4; ++m) {
            aH[m] = *(const short8*)&Ah[wr * 64 + m * 16 + fr][fq * 8];
            aL[m] = *(const short8*)&Al[wr * 64 + m * 16 + fr][fq * 8];
        }
#pragma unroll
        for (int n = 0; n < 4; ++n) {
            bH[n] = *(const short8*)&Bh[wc * 64 + n * 16 + fr][fq * 8];
            bL[n] = *(const short8*)&Bl[wc * 64 + n * 16 + fr][fq * 8];
        }
#pragma unroll
        for (int m = 0; m < 4; ++m)
#pragma unroll
            for (int n = 0; n < 4; ++n) {
                acc[m][n] = __builtin_amdgcn_mfma_f32_16x16x32_bf16(aH[m], bH[n], acc[m][n], 0, 0, 0);
                acc[m][n] = __builtin_amdgcn_mfma_f32_16x16x32_bf16(aH[m], bL[n], acc[m][n], 0, 0, 0);
                acc[m][n] = __builtin_amdgcn_mfma_f32_16x16x32_bf16(aL[m], bH[n], acc[m][n], 0, 0, 0);
            }
        __syncthreads();
    }

    const int s = n0 >> 10;
    float* outp = (s == 0) ? p0 : ((s == 1) ? p1 : p2);
    const int csub = n0 & 1023;
#pragma unroll
    for (int n = 0; n < 4; ++n) {
        const int gcol = wc * 64 + n * 16 + fr;
        const float bv = bias[n0 + gcol];
        const int col = csub + gcol;
#pragma unroll
        for (int m = 0; m < 4; ++m) {
            const int rowb = m0 + wr * 64 + m * 16 + fq * 4;
#pragma unroll
            for (int j = 0; j < 4; ++j)
                outp[(size_t)(rowb + j) * D_ + col] = acc[m][n][j] + bv;
        }
    }
}

// ---------------------------------------------------------------------------
// Causal depthwise conv stage:
//   vout[b,l,d] = ( sum_{t<=l} vin[b,t,d] * filt[l-t,d] ) * gate[b,l,d]
// R9 = R8 structure with the REGISTER BUDGET unlocked:
//   amdgpu_waves_per_eu(2,2) tells the allocator this kernel runs at exactly
//   2 waves/EU (the 128 KB LDS already pins 1 block/CU = 2 waves/EU), so it
//   may use up to 256 VGPRs. R8's __launch_bounds__(512,1) let the compiler
//   target 4 waves/EU -> 128 VGPRs -> ~140 live regs spilled to scratch
//   (WRITE_SIZE 32->154 MB, FETCH 42->101 MB, +20% time).
// Structure (validated correct in R8):
//  - f4[48][128][4] = [quad-row][chan][tap] circular: window quad for chan
//    dl = ONE aligned ds_read_b128; staging transposes 4 taps thru regs.
//  - 512-thread blocks, d-tile 128, l-tile 128 (32 rows/thread), pair
//    {y,15-y} -> 256 uniform blocks on 256 CUs.
//  - static 64-reg circular filter window fwq[16] (f32x4), compile-time
//    indices -> zero shift movs; refresh 4 quads per 4-step group.
//  - vv ping-pong; register prefetch of next tile's v/f.
// ---------------------------------------------------------------------------
__global__ __launch_bounds__(512)
__attribute__((amdgpu_waves_per_eu(2, 2)))
void conv_stage_kernel(
    const float* __restrict__ vin, const float* __restrict__ filt,
    const float* __restrict__ gate, float* __restrict__ vout)
{
    __shared__ float v_lds[64][128];        // [t][d]            32 KB
    __shared__ float f4[48][128][4];        // [qrow][chan][tap] 96 KB circular

    const int d0 = blockIdx.x * 128;
    const int yp = blockIdx.y;         // 0..7
    const int b  = blockIdx.z;
    const int tid = threadIdx.x;
    const int dl = tid & 127;          // channel within tile
    const int rg = tid >> 7;           // 0..3
    const int r0 = rg * 32;            // first of this thread's 32 rows

    const int sr = tid >> 5;           // v staging row 0..15
    const int sc = (tid & 31) * 4;     // v staging col group
    const int fch = tid & 127;         // f staging channel
    const int fq0 = tid >> 7;          // f staging quad-row base 0..3

    const float* vin_b = vin + (size_t)b * L_ * D_;

#define FWQ(i) fwq[((i) & 63) >> 2][(i) & 3]

    for (int half = 0; half < 2; ++half) {
        const int yt = (half == 0) ? yp : (15 - yp);
        const int l0 = yt * 128;
        const int ntiles = 2 * yt + 2;     // t0 = 0 .. l0+64
        int c_cur = l0 % 192;              // sigma base (multiple of 64)

        __syncthreads();   // protect LDS from previous half's compute
        // ---- prologue: stage v tile 0 + full 192-row (48 quad-row) filter ----
        {
#pragma unroll
            for (int s = 0; s < 4; ++s) {
                const float4 q = *(const float4*)&vin_b[(size_t)(sr + 16*s) * D_ + d0 + sc];
                *(float4*)&v_lds[sr + 16*s][sc] = q;
            }
            const int base0 = l0 - 63;
#pragma unroll
            for (int s = 0; s < 12; ++s) {
                const int qr = fq0 + 4*s;            // 0..47
                int qsg = (c_cur >> 2) + qr; if (qsg >= 48) qsg -= 48;
                f32x4 q;
#pragma unroll
                for (int e = 0; e < 4; ++e) {
                    const int a = base0 + 4*qr + e;
                    float fv = 0.f;
                    if (a >= 0 && a < MAXLEN) fv = filt[(size_t)a * D_ + d0 + fch];
                    q[e] = fv;
                }
                *(f32x4*)&f4[qsg][fch][0] = q;
            }
        }
        __syncthreads();

        // ---- prefetch tile 1 (ntiles >= 2 always) ----
        float4 pv[4];
        f32x4 pf4[4];
#pragma unroll
        for (int s = 0; s < 4; ++s)
            pv[s] = *(const float4*)&vin_b[(size_t)(64 + sr + 16*s) * D_ + d0 + sc];
        {
            const int base1 = l0 - 127;   // l0 - 64 - 63
#pragma unroll
            for (int s = 0; s < 4; ++s) {
                const int qr = fq0 + 4*s;            // 0..15
#pragma unroll
                for (int e = 0; e < 4; ++e) {
                    const int a = base1 + 4*qr + e;
                    float fv = 0.f;
                    if (a >= 0 && a < MAXLEN) fv = filt[(size_t)a * D_ + d0 + fch];
                    pf4[s][e] = fv;
                }
            }
        }

        float acc[32];
#pragma unroll
        for (int j = 0; j < 32; ++j) acc[j] = 0.f;

        for (int ti = 0; ti < ntiles; ++ti) {
            // ---- compute tile ti ----
            // init static circular window: i-values K=48..95 -> regs
            // {12..15, 0..7}; regs 8..11 land via the si=0 refresh.
            f32x4 fwq[16];
#pragma unroll
            for (int s2 = 0; s2 < 12; ++s2) {
                const int K = 48 + 4*s2;
                int x = c_cur + r0 + K; if (x >= 192) x -= 192;
                fwq[(K & 63) >> 2] = *(const f32x4*)&f4[x >> 2][dl][0];
            }
            float vv[2][4];
#pragma unroll
            for (int u = 0; u < 4; ++u) vv[0][u] = v_lds[u][dl];

#pragma unroll
            for (int si = 0; si < 16; ++si) {
                const int tb = 4 * si;
                // refresh window for a FUTURE group (target regs dead now)
                if ((si & 3) == 0 && si < 12) {
                    const int g = si >> 2;
#pragma unroll
                    for (int s2 = 0; s2 < 4; ++s2) {
                        const int K = 32 - 16*g + 4*s2;
                        int x = c_cur + r0 + K; if (x >= 192) x -= 192;
                        fwq[(K & 63) >> 2] = *(const f32x4*)&f4[x >> 2][dl][0];
                    }
                }
                // ping-pong: issue next step's v reads
                if (si < 15) {
#pragma unroll
                    for (int u = 0; u < 4; ++u)
                        vv[(si + 1) & 1][u] = v_lds[tb + 4 + u][dl];
                }
                // 128 FMAs; filter tap f[l-t] via static circular reg index
#pragma unroll
                for (int u = 0; u < 4; ++u)
#pragma unroll
                    for (int j = 0; j < 32; ++j)
                        acc[j] += vv[si & 1][u] * FWQ(63 - tb + j - u);
            }

            // ---- stage tile ti+1 from prefetch regs, prefetch ti+2 ----
            if (ti + 1 < ntiles) {
                int c_next = c_cur - 64; if (c_next < 0) c_next += 192;
                __syncthreads();
#pragma unroll
                for (int s = 0; s < 4; ++s)
                    *(float4*)&v_lds[sr + 16*s][sc] = pv[s];
#pragma unroll
                for (int s = 0; s < 4; ++s) {
                    const int qsg = (c_next >> 2) + fq0 + 4*s;   // < 48
                    *(f32x4*)&f4[qsg][fch][0] = pf4[s];
                }
                __syncthreads();
                if (ti + 2 < ntiles) {
                    const int t0n = 64 * (ti + 2);
#pragma unroll
                    for (int s = 0; s < 4; ++s)
                        pv[s] = *(const float4*)&vin_b[(size_t)(t0n + sr + 16*s) * D_ + d0 + sc];
                    const int basen = l0 - t0n - 63;
#pragma unroll
                    for (int s = 0; s < 4; ++s) {
                        const int qr = fq0 + 4*s;
#pragma unroll
                        for (int e = 0; e < 4; ++e) {
                            const int a = basen + 4*qr + e;
                            float fv = 0.f;
                            if (a >= 0 && a < MAXLEN) fv = filt[(size_t)a * D_ + d0 + fch];
                            pf4[s][e] = fv;
                        }
                    }
                }
                c_cur = c_next;
            }
        }

        // ---- gated epilogue ----
        const size_t off = (size_t)b * L_ * D_ + (size_t)l0 * D_ + d0 + dl;
#pragma unroll
        for (int j = 0; j < 32; ++j) {
            const size_t idx = off + (size_t)(r0 + j) * D_;
            vout[idx] = acc[j] * gate[idx];
        }
    }
#undef FWQ
}

extern "C" void kernel_launch(void* const* d_in, const int* in_sizes, int n_in,
                              void* d_out, int out_size, void* d_ws, size_t ws_size,
                              hipStream_t stream) {
    const float* x  = (const float*)d_in[0];   // (B, L, D)
    const float* w  = (const float*)d_in[1];   // (D, 3D)
    const float* bb = (const float*)d_in[2];   // (3D,)
    const float* ft = (const float*)d_in[3];   // (2, 1, MAXLEN, D)
    float* out = (float*)d_out;                // (B, L, D)

    float* p0 = (float*)d_ws;                  // (B*L, D) planar slices
    float* p1 = p0 + (size_t)B_ * L_ * D_;
    float* p2 = p1 + (size_t)B_ * L_ * D_;

    // W split scratch lives in d_out; final conv overwrites all of d_out.
    short* WtH = (short*)d_out;
    short* WtL = WtH + (size_t)N_ * K_;

    // 0) transpose + bf16-split W
    wsplit_kernel<<<dim3(N_ / 64, K_ / 64), 256, 0, stream>>>(w, WtH, WtL);

    // 1) projection GEMM (MFMA bf16x3) -> p0, p1, p2
    gemm_mfma_kernel<<<dim3(N_ / 128, (B_ * L_) / 128), 256, 0, stream>>>(
        x, WtH, WtL, bb, p0, p1, p2);

    // 2) stage 0: v1 = conv(p0, f0) * p1   (in place over p1 — pointwise self-index)
    conv_stage_kernel<<<dim3(D_ / 128, 8, B_), 512, 0, stream>>>(
        p0, ft, p1, p1);

    // 3) stage 1: out = conv(v1, f1) * p2
    conv_stage_kernel<<<dim3(D_ / 128, 8, B_), 512, 0, stream>>>(
        p1, ft + (size_t)MAXLEN * D_, p2, out);
}

// Round 11
// 701.154 us; speedup vs baseline: 1.1327x; 1.1321x over previous
//
#include <hip/hip_runtime.h>
#include <hip/hip_bf16.h>

#define B_     4
#define L_     2048
#define D_     1024
#define MAXLEN 2048
#define N_     3072   // D*(ORDER+1)
#define K_     1024
#define KP     40     // padded LDS row (bf16 elems): 80 B rows, 16B-aligned

typedef __attribute__((ext_vector_type(8))) short short8;
typedef __attribute__((ext_vector_type(4))) short short4v;
typedef __attribute__((ext_vector_type(4))) float f32x4;

__device__ __forceinline__ short f2bf(float x) {
    return __builtin_bit_cast(short, (__bf16)x);
}
__device__ __forceinline__ float bf2f(short h) {
    return (float)__builtin_bit_cast(__bf16, h);
}

// ---------------------------------------------------------------------------
// Prepass: W [K][N] fp32  ->  WtH/WtL [N][K] bf16 (hi/lo split), transposed.
// ---------------------------------------------------------------------------
__global__ __launch_bounds__(256) void wsplit_kernel(
    const float* __restrict__ W, short* __restrict__ WtH, short* __restrict__ WtL)
{
    __shared__ float lds[64][65];
    const int n0 = blockIdx.x * 64;
    const int k0 = blockIdx.y * 64;
    const int t  = threadIdx.x;
    const int nc = t & 63;
#pragma unroll
    for (int i = 0; i < 16; ++i) {
        const int kr = i * 4 + (t >> 6);
        lds[kr][nc] = W[(size_t)(k0 + kr) * N_ + n0 + nc];
    }
    __syncthreads();
    const int kg = (t & 15) * 4;
#pragma unroll
    for (int r = 0; r < 4; ++r) {
        const int nr = (t >> 4) + r * 16;
        short4v hv, lv;
#pragma unroll
        for (int j = 0; j < 4; ++j) {
            const float x = lds[kg + j][nr];
            const short h = f2bf(x);
            hv[j] = h;
            lv[j] = f2bf(x - bf2f(h));
        }
        const size_t o = (size_t)(n0 + nr) * K_ + k0 + kg;
        *(short4v*)&WtH[o] = hv;
        *(short4v*)&WtL[o] = lv;
    }
}

// ---------------------------------------------------------------------------
// GEMM via bf16x3 split MFMA (unchanged from R2).
// ---------------------------------------------------------------------------
__global__ __launch_bounds__(256) void gemm_mfma_kernel(
    const float* __restrict__ X, const short* __restrict__ WtH,
    const short* __restrict__ WtL, const float* __restrict__ bias,
    float* __restrict__ p0, float* __restrict__ p1, float* __restrict__ p2)
{
    __shared__ __align__(16) short Ah[128][KP];
    __shared__ __align__(16) short Al[128][KP];
    __shared__ __align__(16) short Bh[128][KP];
    __shared__ __align__(16) short Bl[128][KP];

    const int tid = threadIdx.x;
    const int m0 = blockIdx.y * 128;
    const int n0 = blockIdx.x * 128;

    const int lane = tid & 63;
    const int wave = tid >> 6;
    const int wr = wave >> 1;
    const int wc = wave & 1;
    const int fr = lane & 15;
    const int fq = lane >> 4;

    const int srow  = tid >> 1;
    const int shalf = (tid & 1) * 16;

    f32x4 acc[4][4];
#pragma unroll
    for (int m = 0; m < 4; ++m)
#pragma unroll
        for (int n = 0; n < 4; ++n) acc[m][n] = (f32x4){0.f, 0.f, 0.f, 0.f};

    const float* xp  = &X[(size_t)(m0 + srow) * K_ + shalf];
    const short* bhp = &WtH[(size_t)(n0 + srow) * K_ + shalf];
    const short* blp = &WtL[(size_t)(n0 + srow) * K_ + shalf];

    for (int k0 = 0; k0 < K_; k0 += 32) {
        float xv[16];
        *(float4*)&xv[0]  = *(const float4*)&xp[k0];
        *(float4*)&xv[4]  = *(const float4*)&xp[k0 + 4];
        *(float4*)&xv[8]  = *(const float4*)&xp[k0 + 8];
        *(float4*)&xv[12] = *(const float4*)&xp[k0 + 12];
        short8 ah[2], al[2];
#pragma unroll
        for (int g = 0; g < 2; ++g)
#pragma unroll
            for (int j = 0; j < 8; ++j) {
                const float x = xv[g * 8 + j];
                const short h = f2bf(x);
                ah[g][j] = h;
                al[g][j] = f2bf(x - bf2f(h));
            }
        *(short8*)&Ah[srow][shalf]     = ah[0];
        *(short8*)&Ah[srow][shalf + 8] = ah[1];
        *(short8*)&Al[srow][shalf]     = al[0];
        *(short8*)&Al[srow][shalf + 8] = al[1];
        *(short8*)&Bh[srow][shalf]     = *(const short8*)&bhp[k0];
        *(short8*)&Bh[srow][shalf + 8] = *(const short8*)&bhp[k0 + 8];
        *(short8*)&Bl[srow][shalf]     = *(const short8*)&blp[k0];
        *(short8*)&Bl[srow][shalf + 8] = *(const short8*)&blp[k0 + 8];
        __syncthreads();

        short8 aH[4], aL[4], bH[4], bL[4];
#pragma unroll
        for (int m = 0; m < 4; ++m) {
            aH[m] = *(const short8*)&Ah[wr * 64 + m * 16 + fr][fq * 8];
            aL[m] = *(const short8*)&Al[wr * 64 + m * 16 + fr][fq * 8];
        }
#pragma unroll
        for (int n = 0; n < 4; ++n) {
            bH[n] = *(const short8*)&Bh[wc * 64 + n * 16 + fr][fq * 8];
            bL[n] = *(const short8*)&Bl[wc * 64 + n * 16 + fr][fq * 8];
        }
#pragma unroll
        for (int m = 0; m < 4; ++m)
#pragma unroll
            for (int n = 0; n < 4; ++n) {
                acc[m][n] = __builtin_amdgcn_mfma_f32_16x16x32_bf16(aH[m], bH[n], acc[m][n], 0, 0, 0);
                acc[m][n] = __builtin_amdgcn_mfma_f32_16x16x32_bf16(aH[m], bL[n], acc[m][n], 0, 0, 0);
                acc[m][n] = __builtin_amdgcn_mfma_f32_16x16x32_bf16(aL[m], bH[n], acc[m][n], 0, 0, 0);
            }
        __syncthreads();
    }

    const int s = n0 >> 10;
    float* outp = (s == 0) ? p0 : ((s == 1) ? p1 : p2);
    const int csub = n0 & 1023;
#pragma unroll
    for (int n = 0; n < 4; ++n) {
        const int gcol = wc * 64 + n * 16 + fr;
        const float bv = bias[n0 + gcol];
        const int col = csub + gcol;
#pragma unroll
        for (int m = 0; m < 4; ++m) {
            const int rowb = m0 + wr * 64 + m * 16 + fq * 4;
#pragma unroll
            for (int j = 0; j < 4; ++j)
                outp[(size_t)(rowb + j) * D_ + col] = acc[m][n][j] + bv;
        }
    }
}

// ---------------------------------------------------------------------------
// Causal depthwise conv stage:
//   vout[b,l,d] = ( sum_{t<=l} vin[b,t,d] * filt[l-t,d] ) * gate[b,l,d]
// R10 = R8 structure, register-dieted to eliminate the 128-VGPR spills:
//  - 12-quad circular filter window (48 regs, was 64): at step si, quads
//    {15-si..23-si} live; one staggered refresh/step loads quad 14-si into
//    slot (14-si)%12, clobbering quad 26-si (dead since step si-3).
//  - NO prefetch registers (was 32): tile ti+1 staged between barriers via
//    short-lived temps; f/v are L2-hot (shared across blocks), ~400cy x 34
//    tiles ~= 6us exposed vs ~40% spill tax removed.
//  - f4[48][128][4] = [quad-row][chan][tap] circular (window quad = ONE
//    aligned ds_read_b128); 512-thread blocks, 128 KB LDS, 1 block/CU,
//    256 uniform blocks; vv ping-pong. All validated in R8.
// ---------------------------------------------------------------------------
__global__ __launch_bounds__(512, 2) void conv_stage_kernel(
    const float* __restrict__ vin, const float* __restrict__ filt,
    const float* __restrict__ gate, float* __restrict__ vout)
{
    __shared__ float v_lds[64][128];        // [t][d]            32 KB
    __shared__ float f4[48][128][4];        // [qrow][chan][tap] 96 KB circular

    const int d0 = blockIdx.x * 128;
    const int yp = blockIdx.y;         // 0..7
    const int b  = blockIdx.z;
    const int tid = threadIdx.x;
    const int dl = tid & 127;          // channel within tile
    const int rg = tid >> 7;           // 0..3
    const int r0 = rg * 32;            // first of this thread's 32 rows

    const int sr = tid >> 5;           // v staging row 0..15
    const int sc = (tid & 31) * 4;     // v staging col group
    const int fch = tid & 127;         // f staging channel
    const int fq0 = tid >> 7;          // f staging quad-row base 0..3

    const float* vin_b = vin + (size_t)b * L_ * D_;

#define FWQ(i) fwq[((i) >> 2) % 12][(i) & 3]

    for (int half = 0; half < 2; ++half) {
        const int yt = (half == 0) ? yp : (15 - yp);
        const int l0 = yt * 128;
        const int ntiles = 2 * yt + 2;     // t0 = 0 .. l0+64
        int c_cur = l0 % 192;              // sigma base (multiple of 64)

        __syncthreads();   // protect LDS from previous half's compute
        // ---- prologue: stage v tile 0 + full 192-row (48 quad-row) filter ----
        {
#pragma unroll
            for (int s = 0; s < 4; ++s) {
                const float4 q = *(const float4*)&vin_b[(size_t)(sr + 16*s) * D_ + d0 + sc];
                *(float4*)&v_lds[sr + 16*s][sc] = q;
            }
            const int base0 = l0 - 63;
#pragma unroll
            for (int s = 0; s < 12; ++s) {
                const int qr = fq0 + 4*s;            // 0..47
                int qsg = (c_cur >> 2) + qr; if (qsg >= 48) qsg -= 48;
                f32x4 q;
#pragma unroll
                for (int e = 0; e < 4; ++e) {
                    const int a = base0 + 4*qr + e;
                    float fv = 0.f;
                    if (a >= 0 && a < MAXLEN) fv = filt[(size_t)a * D_ + d0 + fch];
                    q[e] = fv;
                }
                *(f32x4*)&f4[qsg][fch][0] = q;
            }
        }
        __syncthreads();

        float acc[32];
#pragma unroll
        for (int j = 0; j < 32; ++j) acc[j] = 0.f;

        for (int ti = 0; ti < ntiles; ++ti) {
            // ---- compute tile ti ----
            int base4 = (c_cur + r0) >> 2;          // quad-row base
            if (base4 >= 48) base4 -= 48;           // (c_cur+r0 can reach 224)

            // init 12-slot circular window with quads 15..23 (slots 3..11)
            f32x4 fwq[12];
#pragma unroll
            for (int q = 15; q <= 23; ++q) {
                int x4 = base4 + q; if (x4 >= 48) x4 -= 48;
                fwq[q % 12] = *(const f32x4*)&f4[x4][dl][0];
            }
            float vv[2][4];
#pragma unroll
            for (int u = 0; u < 4; ++u) vv[0][u] = v_lds[u][dl];

#pragma unroll
            for (int si = 0; si < 16; ++si) {
                const int tb = 4 * si;
                if (si < 15) {
                    // staggered refresh: quad 14-si first needed at step si+1;
                    // slot (14-si)%12 holds quad 26-si, dead since step si-3.
                    const int q = 14 - si;
                    int x4 = base4 + q; if (x4 >= 48) x4 -= 48;
                    fwq[q % 12] = *(const f32x4*)&f4[x4][dl][0];
                    // ping-pong: next step's v reads
#pragma unroll
                    for (int u = 0; u < 4; ++u)
                        vv[(si + 1) & 1][u] = v_lds[tb + 4 + u][dl];
                }
                // 128 FMAs; tap f[l-t] at window coord i = 63-tb+j-u (0..94)
#pragma unroll
                for (int u = 0; u < 4; ++u)
#pragma unroll
                    for (int j = 0; j < 32; ++j)
                        acc[j] += vv[si & 1][u] * FWQ(63 - tb + j - u);
            }

            // ---- stage tile ti+1 directly (short-lived temps, no prefetch) ----
            if (ti + 1 < ntiles) {
                int c_next = c_cur - 64; if (c_next < 0) c_next += 192;
                const int t0n = 64 * (ti + 1);
                const int basen = l0 - t0n - 63;
                __syncthreads();
                float4 tv[4];
                f32x4 tf[4];
#pragma unroll
                for (int s = 0; s < 4; ++s)
                    tv[s] = *(const float4*)&vin_b[(size_t)(t0n + sr + 16*s) * D_ + d0 + sc];
#pragma unroll
                for (int s = 0; s < 4; ++s) {
                    const int qr = fq0 + 4*s;            // 0..15
#pragma unroll
                    for (int e = 0; e < 4; ++e) {
                        const int a = basen + 4*qr + e;
                        float fv = 0.f;
                        if (a >= 0 && a < MAXLEN) fv = filt[(size_t)a * D_ + d0 + fch];
                        tf[s][e] = fv;
                    }
                }
#pragma unroll
                for (int s = 0; s < 4; ++s)
                    *(float4*)&v_lds[sr + 16*s][sc] = tv[s];
#pragma unroll
                for (int s = 0; s < 4; ++s) {
                    const int qsg = (c_next >> 2) + fq0 + 4*s;   // < 48
                    *(f32x4*)&f4[qsg][fch][0] = tf[s];
                }
                __syncthreads();
                c_cur = c_next;
            }
        }

        // ---- gated epilogue ----
        const size_t off = (size_t)b * L_ * D_ + (size_t)l0 * D_ + d0 + dl;
#pragma unroll
        for (int j = 0; j < 32; ++j) {
            const size_t idx = off + (size_t)(r0 + j) * D_;
            vout[idx] = acc[j] * gate[idx];
        }
    }
#undef FWQ
}

extern "C" void kernel_launch(void* const* d_in, const int* in_sizes, int n_in,
                              void* d_out, int out_size, void* d_ws, size_t ws_size,
                              hipStream_t stream) {
    const float* x  = (const float*)d_in[0];   // (B, L, D)
    const float* w  = (const float*)d_in[1];   // (D, 3D)
    const float* bb = (const float*)d_in[2];   // (3D,)
    const float* ft = (const float*)d_in[3];   // (2, 1, MAXLEN, D)
    float* out = (float*)d_out;                // (B, L, D)

    float* p0 = (float*)d_ws;                  // (B*L, D) planar slices
    float* p1 = p0 + (size_t)B_ * L_ * D_;
    float* p2 = p1 + (size_t)B_ * L_ * D_;

    // W split scratch lives in d_out; final conv overwrites all of d_out.
    short* WtH = (short*)d_out;
    short* WtL = WtH + (size_t)N_ * K_;

    // 0) transpose + bf16-split W
    wsplit_kernel<<<dim3(N_ / 64, K_ / 64), 256, 0, stream>>>(w, WtH, WtL);

    // 1) projection GEMM (MFMA bf16x3) -> p0, p1, p2
    gemm_mfma_kernel<<<dim3(N_ / 128, (B_ * L_) / 128), 256, 0, stream>>>(
        x, WtH, WtL, bb, p0, p1, p2);

    // 2) stage 0: v1 = conv(p0, f0) * p1   (in place over p1 — pointwise self-index)
    conv_stage_kernel<<<dim3(D_ / 128, 8, B_), 512, 0, stream>>>(
        p0, ft, p1, p1);

    // 3) stage 1: out = conv(v1, f1) * p2
    conv_stage_kernel<<<dim3(D_ / 128, 8, B_), 512, 0, stream>>>(
        p1, ft + (size_t)MAXLEN * D_, p2, out);
}

// Round 12
// 688.899 us; speedup vs baseline: 1.1529x; 1.0178x over previous
//
#include <hip/hip_runtime.h>
#include <hip/hip_bf16.h>

#define B_     4
#define L_     2048
#define D_     1024
#define MAXLEN 2048
#define N_     3072   // D*(ORDER+1)
#define K_     1024
#define KP     40     // padded LDS row (bf16 elems): 80 B rows, 16B-aligned

typedef __attribute__((ext_vector_type(8))) short short8;
typedef __attribute__((ext_vector_type(4))) short short4v;
typedef __attribute__((ext_vector_type(4))) float f32x4;

__device__ __forceinline__ short f2bf(float x) {
    return __builtin_bit_cast(short, (__bf16)x);
}
__device__ __forceinline__ float bf2f(short h) {
    return (float)__builtin_bit_cast(__bf16, h);
}

// ---------------------------------------------------------------------------
// Prepass: W [K][N] fp32  ->  WtH/WtL [N][K] bf16 (hi/lo split), transposed.
// ---------------------------------------------------------------------------
__global__ __launch_bounds__(256) void wsplit_kernel(
    const float* __restrict__ W, short* __restrict__ WtH, short* __restrict__ WtL)
{
    __shared__ float lds[64][65];
    const int n0 = blockIdx.x * 64;
    const int k0 = blockIdx.y * 64;
    const int t  = threadIdx.x;
    const int nc = t & 63;
#pragma unroll
    for (int i = 0; i < 16; ++i) {
        const int kr = i * 4 + (t >> 6);
        lds[kr][nc] = W[(size_t)(k0 + kr) * N_ + n0 + nc];
    }
    __syncthreads();
    const int kg = (t & 15) * 4;
#pragma unroll
    for (int r = 0; r < 4; ++r) {
        const int nr = (t >> 4) + r * 16;
        short4v hv, lv;
#pragma unroll
        for (int j = 0; j < 4; ++j) {
            const float x = lds[kg + j][nr];
            const short h = f2bf(x);
            hv[j] = h;
            lv[j] = f2bf(x - bf2f(h));
        }
        const size_t o = (size_t)(n0 + nr) * K_ + k0 + kg;
        *(short4v*)&WtH[o] = hv;
        *(short4v*)&WtL[o] = lv;
    }
}

// ---------------------------------------------------------------------------
// GEMM via bf16x3 split MFMA (unchanged from R2).
// ---------------------------------------------------------------------------
__global__ __launch_bounds__(256) void gemm_mfma_kernel(
    const float* __restrict__ X, const short* __restrict__ WtH,
    const short* __restrict__ WtL, const float* __restrict__ bias,
    float* __restrict__ p0, float* __restrict__ p1, float* __restrict__ p2)
{
    __shared__ __align__(16) short Ah[128][KP];
    __shared__ __align__(16) short Al[128][KP];
    __shared__ __align__(16) short Bh[128][KP];
    __shared__ __align__(16) short Bl[128][KP];

    const int tid = threadIdx.x;
    const int m0 = blockIdx.y * 128;
    const int n0 = blockIdx.x * 128;

    const int lane = tid & 63;
    const int wave = tid >> 6;
    const int wr = wave >> 1;
    const int wc = wave & 1;
    const int fr = lane & 15;
    const int fq = lane >> 4;

    const int srow  = tid >> 1;
    const int shalf = (tid & 1) * 16;

    f32x4 acc[4][4];
#pragma unroll
    for (int m = 0; m < 4; ++m)
#pragma unroll
        for (int n = 0; n < 4; ++n) acc[m][n] = (f32x4){0.f, 0.f, 0.f, 0.f};

    const float* xp  = &X[(size_t)(m0 + srow) * K_ + shalf];
    const short* bhp = &WtH[(size_t)(n0 + srow) * K_ + shalf];
    const short* blp = &WtL[(size_t)(n0 + srow) * K_ + shalf];

    for (int k0 = 0; k0 < K_; k0 += 32) {
        float xv[16];
        *(float4*)&xv[0]  = *(const float4*)&xp[k0];
        *(float4*)&xv[4]  = *(const float4*)&xp[k0 + 4];
        *(float4*)&xv[8]  = *(const float4*)&xp[k0 + 8];
        *(float4*)&xv[12] = *(const float4*)&xp[k0 + 12];
        short8 ah[2], al[2];
#pragma unroll
        for (int g = 0; g < 2; ++g)
#pragma unroll
            for (int j = 0; j < 8; ++j) {
                const float x = xv[g * 8 + j];
                const short h = f2bf(x);
                ah[g][j] = h;
                al[g][j] = f2bf(x - bf2f(h));
            }
        *(short8*)&Ah[srow][shalf]     = ah[0];
        *(short8*)&Ah[srow][shalf + 8] = ah[1];
        *(short8*)&Al[srow][shalf]     = al[0];
        *(short8*)&Al[srow][shalf + 8] = al[1];
        *(short8*)&Bh[srow][shalf]     = *(const short8*)&bhp[k0];
        *(short8*)&Bh[srow][shalf + 8] = *(const short8*)&bhp[k0 + 8];
        *(short8*)&Bl[srow][shalf]     = *(const short8*)&blp[k0];
        *(short8*)&Bl[srow][shalf + 8] = *(const short8*)&blp[k0 + 8];
        __syncthreads();

        short8 aH[4], aL[4], bH[4], bL[4];
#pragma unroll
        for (int m = 0; m < 4; ++m) {
            aH[m] = *(const short8*)&Ah[wr * 64 + m * 16 + fr][fq * 8];
            aL[m] = *(const short8*)&Al[wr * 64 + m * 16 + fr][fq * 8];
        }
#pragma unroll
        for (int n = 0; n < 4; ++n) {
            bH[n] = *(const short8*)&Bh[wc * 64 + n * 16 + fr][fq * 8];
            bL[n] = *(const short8*)&Bl[wc * 64 + n * 16 + fr][fq * 8];
        }
#pragma unroll
        for (int m = 0; m < 4; ++m)
#pragma unroll
            for (int n = 0; n < 4; ++n) {
                acc[m][n] = __builtin_amdgcn_mfma_f32_16x16x32_bf16(aH[m], bH[n], acc[m][n], 0, 0, 0);
                acc[m][n] = __builtin_amdgcn_mfma_f32_16x16x32_bf16(aH[m], bL[n], acc[m][n], 0, 0, 0);
                acc[m][n] = __builtin_amdgcn_mfma_f32_16x16x32_bf16(aL[m], bH[n], acc[m][n], 0, 0, 0);
            }
        __syncthreads();
    }

    const int s = n0 >> 10;
    float* outp = (s == 0) ? p0 : ((s == 1) ? p1 : p2);
    const int csub = n0 & 1023;
#pragma unroll
    for (int n = 0; n < 4; ++n) {
        const int gcol = wc * 64 + n * 16 + fr;
        const float bv = bias[n0 + gcol];
        const int col = csub + gcol;
#pragma unroll
        for (int m = 0; m < 4; ++m) {
            const int rowb = m0 + wr * 64 + m * 16 + fq * 4;
#pragma unroll
            for (int j = 0; j < 4; ++j)
                outp[(size_t)(rowb + j) * D_ + col] = acc[m][n][j] + bv;
        }
    }
}

// ---------------------------------------------------------------------------
// Causal depthwise conv stage:
//   vout[b,l,d] = ( sum_{t<=l} vin[b,t,d] * filt[l-t,d] ) * gate[b,l,d]
// R11 = R6 geometry + R10 compute core, spill-free:
//  - 256-thread blocks, d-tile 64, l-tile 128 (32 rows/thread), pair
//    {y,15-y} -> 512 uniform blocks; 64 KB LDS -> 2 blocks/CU (one block
//    computes while the other sits at staging barriers).
//  - f4[48][64][4] = [quad-row][chan][tap] circular: window quad for chan
//    dl = ONE aligned ds_read_b128 (validated in R8/R10).
//  - 12-quad circular register window, compile-time indices -> zero shift
//    movs; staggered single-quad refresh/step into provably-dead slots.
//  - direct staging between barriers (no prefetch regs): live set ~105
//    fits the de-facto 128-VGPR cap -> no scratch spills (R8-R10 spilled
//    ~40-120 MB; R10 WRITE_SIZE 75 MB vs 32 MB output).
//  - vv ping-pong for v reads.
// ---------------------------------------------------------------------------
__global__ __launch_bounds__(256, 2) void conv_stage_kernel(
    const float* __restrict__ vin, const float* __restrict__ filt,
    const float* __restrict__ gate, float* __restrict__ vout)
{
    __shared__ float v_lds[64][64];         // [t][d]            16 KB
    __shared__ float f4[48][64][4];         // [qrow][chan][tap] 48 KB circular

    const int d0 = blockIdx.x * 64;
    const int yp = blockIdx.y;         // 0..7
    const int b  = blockIdx.z;
    const int tid = threadIdx.x;
    const int dl = tid & 63;           // channel within tile
    const int rg = tid >> 6;           // 0..3
    const int r0 = rg * 32;            // first of this thread's 32 rows

    const int sr = tid >> 4;           // v staging row 0..15
    const int sc = (tid & 15) * 4;     // v staging col group
    const int fch = tid & 63;          // f staging channel
    const int fq0 = tid >> 6;          // f staging quad-row base 0..3

    const float* vin_b = vin + (size_t)b * L_ * D_;

#define FWQ(i) fwq[((i) >> 2) % 12][(i) & 3]

    for (int half = 0; half < 2; ++half) {
        const int yt = (half == 0) ? yp : (15 - yp);
        const int l0 = yt * 128;
        const int ntiles = 2 * yt + 2;     // t0 = 0 .. l0+64
        int c_cur = l0 % 192;              // sigma base (multiple of 64)

        __syncthreads();   // protect LDS from previous half's compute
        // ---- prologue: stage v tile 0 + full 48-quad-row filter window ----
        {
#pragma unroll
            for (int s = 0; s < 4; ++s) {
                const float4 q = *(const float4*)&vin_b[(size_t)(sr + 16*s) * D_ + d0 + sc];
                *(float4*)&v_lds[sr + 16*s][sc] = q;
            }
            const int base0 = l0 - 63;
#pragma unroll
            for (int s = 0; s < 12; ++s) {
                const int qr = fq0 + 4*s;            // 0..47
                int qsg = (c_cur >> 2) + qr; if (qsg >= 48) qsg -= 48;
                f32x4 q;
#pragma unroll
                for (int e = 0; e < 4; ++e) {
                    const int a = base0 + 4*qr + e;
                    float fv = 0.f;
                    if (a >= 0 && a < MAXLEN) fv = filt[(size_t)a * D_ + d0 + fch];
                    q[e] = fv;
                }
                *(f32x4*)&f4[qsg][fch][0] = q;
            }
        }
        __syncthreads();

        float acc[32];
#pragma unroll
        for (int j = 0; j < 32; ++j) acc[j] = 0.f;

        for (int ti = 0; ti < ntiles; ++ti) {
            // ---- compute tile ti ----
            int base4 = (c_cur + r0) >> 2;          // quad-row base
            if (base4 >= 48) base4 -= 48;           // (c_cur+r0 can reach 224)

            // init 12-slot circular window with quads 15..23 (slots 3..11)
            f32x4 fwq[12];
#pragma unroll
            for (int q = 15; q <= 23; ++q) {
                int x4 = base4 + q; if (x4 >= 48) x4 -= 48;
                fwq[q % 12] = *(const f32x4*)&f4[x4][dl][0];
            }
            float vv[2][4];
#pragma unroll
            for (int u = 0; u < 4; ++u) vv[0][u] = v_lds[u][dl];

#pragma unroll
            for (int si = 0; si < 16; ++si) {
                const int tb = 4 * si;
                if (si < 15) {
                    // staggered refresh: quad 14-si first needed at step si+1;
                    // slot (14-si)%12 holds quad 26-si, dead since step si-3.
                    const int q = 14 - si;
                    int x4 = base4 + q; if (x4 >= 48) x4 -= 48;
                    fwq[q % 12] = *(const f32x4*)&f4[x4][dl][0];
                    // ping-pong: next step's v reads
#pragma unroll
                    for (int u = 0; u < 4; ++u)
                        vv[(si + 1) & 1][u] = v_lds[tb + 4 + u][dl];
                }
                // 128 FMAs; tap f[l-t] at window coord i = 63-tb+j-u (0..94)
#pragma unroll
                for (int u = 0; u < 4; ++u)
#pragma unroll
                    for (int j = 0; j < 32; ++j)
                        acc[j] += vv[si & 1][u] * FWQ(63 - tb + j - u);
            }

            // ---- stage tile ti+1 directly (short-lived temps) ----
            if (ti + 1 < ntiles) {
                int c_next = c_cur - 64; if (c_next < 0) c_next += 192;
                const int t0n = 64 * (ti + 1);
                const int basen = l0 - t0n - 63;
                __syncthreads();
                float4 tv[4];
                f32x4 tf[4];
#pragma unroll
                for (int s = 0; s < 4; ++s)
                    tv[s] = *(const float4*)&vin_b[(size_t)(t0n + sr + 16*s) * D_ + d0 + sc];
#pragma unroll
                for (int s = 0; s < 4; ++s) {
                    const int qr = fq0 + 4*s;            // 0..15
#pragma unroll
                    for (int e = 0; e < 4; ++e) {
                        const int a = basen + 4*qr + e;
                        float fv = 0.f;
                        if (a >= 0 && a < MAXLEN) fv = filt[(size_t)a * D_ + d0 + fch];
                        tf[s][e] = fv;
                    }
                }
#pragma unroll
                for (int s = 0; s < 4; ++s)
                    *(float4*)&v_lds[sr + 16*s][sc] = tv[s];
#pragma unroll
                for (int s = 0; s < 4; ++s) {
                    const int qsg = (c_next >> 2) + fq0 + 4*s;   // < 48
                    *(f32x4*)&f4[qsg][fch][0] = tf[s];
                }
                __syncthreads();
                c_cur = c_next;
            }
        }

        // ---- gated epilogue ----
        const size_t off = (size_t)b * L_ * D_ + (size_t)l0 * D_ + d0 + dl;
#pragma unroll
        for (int j = 0; j < 32; ++j) {
            const size_t idx = off + (size_t)(r0 + j) * D_;
            vout[idx] = acc[j] * gate[idx];
        }
    }
#undef FWQ
}

extern "C" void kernel_launch(void* const* d_in, const int* in_sizes, int n_in,
                              void* d_out, int out_size, void* d_ws, size_t ws_size,
                              hipStream_t stream) {
    const float* x  = (const float*)d_in[0];   // (B, L, D)
    const float* w  = (const float*)d_in[1];   // (D, 3D)
    const float* bb = (const float*)d_in[2];   // (3D,)
    const float* ft = (const float*)d_in[3];   // (2, 1, MAXLEN, D)
    float* out = (float*)d_out;                // (B, L, D)

    float* p0 = (float*)d_ws;                  // (B*L, D) planar slices
    float* p1 = p0 + (size_t)B_ * L_ * D_;
    float* p2 = p1 + (size_t)B_ * L_ * D_;

    // W split scratch lives in d_out; final conv overwrites all of d_out.
    short* WtH = (short*)d_out;
    short* WtL = WtH + (size_t)N_ * K_;

    // 0) transpose + bf16-split W
    wsplit_kernel<<<dim3(N_ / 64, K_ / 64), 256, 0, stream>>>(w, WtH, WtL);

    // 1) projection GEMM (MFMA bf16x3) -> p0, p1, p2
    gemm_mfma_kernel<<<dim3(N_ / 128, (B_ * L_) / 128), 256, 0, stream>>>(
        x, WtH, WtL, bb, p0, p1, p2);

    // 2) stage 0: v1 = conv(p0, f0) * p1   (in place over p1 — pointwise self-index)
    conv_stage_kernel<<<dim3(D_ / 64, 8, B_), 256, 0, stream>>>(
        p0, ft, p1, p1);

    // 3) stage 1: out = conv(v1, f1) * p2
    conv_stage_kernel<<<dim3(D_ / 64, 8, B_), 256, 0, stream>>>(
        p1, ft + (size_t)MAXLEN * D_, p2, out);
}